// Round 9
// baseline (564.780 us; speedup 1.0000x reference)
//
#include <hip/hip_runtime.h>

// GCN 3-layer encoder: bucket-binned CSR build + phased wave-gather layers.
// Build: hist -> bucket scan -> bin (packed src<<9|dstLocal, contiguous
// single-XCD writes) -> per-bucket counting sort into dst-sorted CSR.
// Layer 2 gather sweeps sources in 16K-node windows (2MB, L2-resident) with a
// resident grid + per-phase barrier, so all co-resident blocks touch the same
// p2 window at the same time (round-7 evidence: unphased random gather fetched
// 294MB of a 12.8MB array from L3 at 2.3TB/s = the whole 129us).
// Aggregation on the narrower side (A@(H W) = (A@H)@W); norm folded as
// p = dinv*h ; agg = sum p[src] ; out = dinv*(agg + p_self).

#define G_GRAPHS 128
#define BK_SHIFT 9
#define BK 512        // dst nodes per bucket
#define NB_MAX 256    // max buckets
#define PH_SHIFT 14   // 16384-src window per phase (2MB of p2)
#define GRID2 2048    // resident grid for phased gather (8 blocks/CU)

// K1: global bucket histogram (grid-stride, LDS-staged)
__global__ void hist_kernel(const int* __restrict__ dst, int* __restrict__ bcnt,
                            int E, int nb) {
    __shared__ int h[NB_MAX];
    for (int t = threadIdx.x; t < NB_MAX; t += blockDim.x) h[t] = 0;
    __syncthreads();
    for (int e = blockIdx.x * blockDim.x + threadIdx.x; e < E; e += gridDim.x * blockDim.x)
        atomicAdd(&h[dst[e] >> BK_SHIFT], 1);
    __syncthreads();
    for (int t = threadIdx.x; t < nb; t += blockDim.x)
        if (h[t]) atomicAdd(&bcnt[t], h[t]);
}

// K2: single-block exclusive scan of bucket counts -> boff, cursor (nb <= 256)
__global__ void bscan_kernel(const int* __restrict__ bcnt, int* __restrict__ boff,
                             int* __restrict__ cursor, int nb) {
    __shared__ int tmp[NB_MAX];
    int t = threadIdx.x;
    int v = (t < nb) ? bcnt[t] : 0;
    tmp[t] = v;
    __syncthreads();
    for (int off = 1; off < NB_MAX; off <<= 1) {
        int u = (t >= off) ? tmp[t - off] : 0;
        __syncthreads();
        tmp[t] += u;
        __syncthreads();
    }
    if (t < nb) {
        int excl = tmp[t] - v;
        boff[t] = excl;
        cursor[t] = excl;
    }
    if (t == nb - 1) boff[nb] = tmp[t];
}

// K3: bin edges into buckets with per-(block,bucket) chunked reservation.
__global__ void bin_kernel(const int* __restrict__ src, const int* __restrict__ dst,
                           int* __restrict__ cursor, unsigned* __restrict__ bedge,
                           int E, int nb, int chunk) {
    __shared__ int lcnt[NB_MAX];
    __shared__ int lbase[NB_MAX];
    int start = blockIdx.x * chunk;
    int end = min(start + chunk, E);
    for (int t = threadIdx.x; t < NB_MAX; t += blockDim.x) lcnt[t] = 0;
    __syncthreads();
    for (int e = start + threadIdx.x; e < end; e += blockDim.x)
        atomicAdd(&lcnt[dst[e] >> BK_SHIFT], 1);
    __syncthreads();
    for (int t = threadIdx.x; t < nb; t += blockDim.x) {
        int c = lcnt[t];
        lbase[t] = c ? atomicAdd(&cursor[t], c) : 0;
    }
    __syncthreads();
    for (int t = threadIdx.x; t < NB_MAX; t += blockDim.x) lcnt[t] = 0;
    __syncthreads();
    for (int e = start + threadIdx.x; e < end; e += blockDim.x) {
        int d = dst[e];
        int bk = d >> BK_SHIFT;
        int pos = lbase[bk] + atomicAdd(&lcnt[bk], 1);
        bedge[pos] = ((unsigned)src[e] << BK_SHIFT) | (unsigned)(d & (BK - 1));
    }
}

// K4: per-bucket counting sort -> dst-sorted CSR, fused with woff, dinv,
// p1 = dinv*x (padded to float4 so layer1 gathers one dwordx4 per edge).
__global__ __launch_bounds__(512) void sort_build(
    const unsigned* __restrict__ bedge, const int* __restrict__ boff,
    const float* __restrict__ x, int* __restrict__ csr, int* __restrict__ woff,
    float* __restrict__ dinv, float* __restrict__ p1, int n, int E) {
    __shared__ int hist[BK];
    __shared__ int scan[BK];
    __shared__ int cur[BK];
    int b = blockIdx.x;
    int beg = boff[b], end = boff[b + 1];
    int t = threadIdx.x;
    hist[t] = 0;
    __syncthreads();
    for (int e = beg + t; e < end; e += 512)
        atomicAdd(&hist[bedge[e] & (BK - 1)], 1);
    __syncthreads();
    int v = hist[t];
    scan[t] = v;
    __syncthreads();
    for (int off = 1; off < BK; off <<= 1) {
        int u = (t >= off) ? scan[t - off] : 0;
        __syncthreads();
        scan[t] += u;
        __syncthreads();
    }
    int excl = scan[t] - v;
    int i = (b << BK_SHIFT) + t;
    if (i < n) {
        woff[i] = beg + excl;
        float di = rsqrtf((float)v + 1.0f);
        dinv[i] = di;
        *reinterpret_cast<float4*>(p1 + 4 * (size_t)i) =
            make_float4(di * x[3 * i + 0], di * x[3 * i + 1], di * x[3 * i + 2], 0.0f);
    }
    if (b == 0 && t == 0) woff[n] = E;
    cur[t] = beg + excl;
    __syncthreads();
    for (int e = beg + t; e < end; e += 512) {
        unsigned u = bedge[e];
        int pos = atomicAdd(&cur[u & (BK - 1)], 1);
        csr[pos] = (int)(u >> BK_SHIFT);
    }
}

// ---- Layers ---------------------------------------------------------------

// thread/node: gather float4 p1 rows, s = dinv*(sum + self), p2 = dinv*relu(s@W1+b1)
__global__ void layer1_fused(const int* __restrict__ csr, const int* __restrict__ woff,
                             const float* __restrict__ p1, const float* __restrict__ dinv,
                             const float* __restrict__ W1, const float* __restrict__ b1,
                             float* __restrict__ p2, int n) {
    __shared__ float w[96];
    __shared__ float bb[32];
    for (int t = threadIdx.x; t < 96; t += blockDim.x) w[t] = W1[t];
    for (int t = threadIdx.x; t < 32; t += blockDim.x) bb[t] = b1[t];
    __syncthreads();
    int i = blockIdx.x * blockDim.x + threadIdx.x;
    if (i >= n) return;
    int beg = woff[i], end = woff[i + 1];
    float s0 = 0.f, s1 = 0.f, s2 = 0.f;
    for (int k = beg; k < end; ++k) {
        int s = csr[k];
        const float4 v = *reinterpret_cast<const float4*>(p1 + 4 * (size_t)s);
        s0 += v.x; s1 += v.y; s2 += v.z;
    }
    float d = dinv[i];
    const float4 sf = *reinterpret_cast<const float4*>(p1 + 4 * (size_t)i);
    s0 = d * (s0 + sf.x);
    s1 = d * (s1 + sf.y);
    s2 = d * (s2 + sf.z);
#pragma unroll
    for (int q = 0; q < 8; ++q) {
        float o[4];
#pragma unroll
        for (int c = 0; c < 4; ++c) {
            int j = q * 4 + c;
            float h = fmaf(s0, w[j], fmaf(s1, w[32 + j], fmaf(s2, w[64 + j], bb[j])));
            o[c] = d * fmaxf(h, 0.0f);
        }
        *reinterpret_cast<float4*>(p2 + 32 * (size_t)i + 4 * q) =
            make_float4(o[0], o[1], o[2], o[3]);
    }
}

// Phased wave-gather layer 2. Resident grid (GRID2 blocks); each wave owns
// <=13 nodes (npb<=52) whose 32-float accumulators persist in registers:
// lane-group g=lane>>3 holds nodes j==g (mod 8), reg j>>3, as float4 per
// lane (part=lane&7). Per phase x only edges with src>>PH_SHIFT==x gather,
// then a block barrier keeps all resident waves in the same 2MB p2 window.
__global__ __launch_bounds__(256, 8) void gather2_phased(
    const int* __restrict__ csr, const int* __restrict__ woff,
    const float* __restrict__ p2, const float* __restrict__ dinv,
    const float* __restrict__ W2, const float* __restrict__ b2,
    const float* __restrict__ W3, float* __restrict__ p3,
    int n, int npb, int nphase) {
    __shared__ float w2[32 * 64];
    __shared__ float b2s[64];
    __shared__ float w3[128];
    for (int t = threadIdx.x; t < 32 * 64; t += 256) w2[t] = W2[t];
    if (threadIdx.x < 64)  b2s[threadIdx.x] = b2[threadIdx.x];
    if (threadIdx.x < 128) w3[threadIdx.x] = W3[threadIdx.x];
    __syncthreads();

    int lane = threadIdx.x & 63;
    int w = threadIdx.x >> 6;
    int base = blockIdx.x * npb;
    int lim = min(base + npb, n);
    int part = lane & 7;   // float4 part of the 32-float row
    int slot = lane >> 3;  // edge slot / holder group
    float4 acc0 = {0.f, 0.f, 0.f, 0.f};  // nodes j=0..7
    float4 acc1 = {0.f, 0.f, 0.f, 0.f};  // nodes j=8..15

    for (int x = 0; x < nphase; ++x) {
        int j = 0;
        for (int i = base + w; i < lim; i += 4, ++j) {
            int beg = woff[i];
            int dg = woff[i + 1] - beg;
            float4 a = {0.f, 0.f, 0.f, 0.f};
            for (int k = slot; k < dg; k += 8) {
                int s = csr[beg + k];
                if ((s >> PH_SHIFT) == x) {
                    const float4 v =
                        *reinterpret_cast<const float4*>(p2 + 32 * (size_t)s + 4 * part);
                    a.x += v.x; a.y += v.y; a.z += v.z; a.w += v.w;
                }
            }
#pragma unroll
            for (int m = 8; m <= 32; m <<= 1) {
                a.x += __shfl_xor(a.x, m, 64);
                a.y += __shfl_xor(a.y, m, 64);
                a.z += __shfl_xor(a.z, m, 64);
                a.w += __shfl_xor(a.w, m, 64);
            }
            if (slot == (j & 7)) {
                if (j < 8) { acc0.x += a.x; acc0.y += a.y; acc0.z += a.z; acc0.w += a.w; }
                else       { acc1.x += a.x; acc1.y += a.y; acc1.z += a.z; acc1.w += a.w; }
            }
        }
        __syncthreads();  // all resident waves advance to the next src window
    }

    // Epilogue: per node, broadcast row from holder lanes, add self, transform.
    int j = 0;
    for (int i = base + w; i < lim; i += 4, ++j) {
        int hl = ((j & 7) << 3) + part;  // holder lane for my part
        float4 hold = (j < 8) ? acc0 : acc1;
        float4 r;
        r.x = __shfl(hold.x, hl, 64);
        r.y = __shfl(hold.y, hl, 64);
        r.z = __shfl(hold.z, hl, 64);
        r.w = __shfl(hold.w, hl, 64);
        float d = dinv[i];
        const float4 sv = *reinterpret_cast<const float4*>(p2 + 32 * (size_t)i + 4 * part);
        float4 sc;
        sc.x = d * (r.x + sv.x);
        sc.y = d * (r.y + sv.y);
        sc.z = d * (r.z + sv.z);
        sc.w = d * (r.w + sv.w);
        // lane jj computes h2[jj]; part p of the input lives on lane p
        int jj = lane;
        float h = b2s[jj];
#pragma unroll
        for (int p = 0; p < 8; ++p) {
            float s0 = __shfl(sc.x, p, 64);
            float s1 = __shfl(sc.y, p, 64);
            float s2 = __shfl(sc.z, p, 64);
            float s3 = __shfl(sc.w, p, 64);
            h = fmaf(s0, w2[(4 * p + 0) * 64 + jj], h);
            h = fmaf(s1, w2[(4 * p + 1) * 64 + jj], h);
            h = fmaf(s2, w2[(4 * p + 2) * 64 + jj], h);
            h = fmaf(s3, w2[(4 * p + 3) * 64 + jj], h);
        }
        h = fmaxf(h, 0.0f);
        float a0 = h * w3[2 * jj + 0];
        float a1 = h * w3[2 * jj + 1];
#pragma unroll
        for (int m = 1; m < 64; m <<= 1) {
            a0 += __shfl_xor(a0, m, 64);
            a1 += __shfl_xor(a1, m, 64);
        }
        if (lane == 0) {
            p3[2 * (size_t)i + 0] = d * a0;
            p3[2 * (size_t)i + 1] = d * a1;
        }
    }
}

// thread/node: gather 2-wide rows, epilogue + mean-pool (LDS bins -> global atomics)
__global__ void layer3_pool(const int* __restrict__ csr, const int* __restrict__ woff,
                            const float* __restrict__ p3, const float* __restrict__ dinv,
                            const int* __restrict__ batch, const float* __restrict__ b3,
                            float* __restrict__ sums, float* __restrict__ cnt, int n) {
    __shared__ float ls[G_GRAPHS * 2];
    __shared__ float lc[G_GRAPHS];
    for (int t = threadIdx.x; t < G_GRAPHS * 2; t += blockDim.x) ls[t] = 0.0f;
    for (int t = threadIdx.x; t < G_GRAPHS; t += blockDim.x) lc[t] = 0.0f;
    __syncthreads();
    int i = blockIdx.x * blockDim.x + threadIdx.x;
    if (i < n) {
        int beg = woff[i], end = woff[i + 1];
        float a0 = 0.f, a1 = 0.f;
        for (int k = beg; k < end; ++k) {
            int s = csr[k];
            a0 += p3[2 * (size_t)s + 0];
            a1 += p3[2 * (size_t)s + 1];
        }
        float d = dinv[i];
        float v0 = fmaf(d, a0 + p3[2 * (size_t)i + 0], b3[0]);
        float v1 = fmaf(d, a1 + p3[2 * (size_t)i + 1], b3[1]);
        int g = batch[i];
        atomicAdd(&ls[2 * g + 0], v0);
        atomicAdd(&ls[2 * g + 1], v1);
        atomicAdd(&lc[g], 1.0f);
    }
    __syncthreads();
    for (int g = threadIdx.x; g < G_GRAPHS; g += blockDim.x) {
        float c = lc[g];
        if (c != 0.0f) {
            atomicAdd(&sums[2 * g + 0], ls[2 * g + 0]);
            atomicAdd(&sums[2 * g + 1], ls[2 * g + 1]);
            atomicAdd(&cnt[g], c);
        }
    }
}

__global__ void finalize_kernel(const float* __restrict__ sums, const float* __restrict__ cnt,
                                float* __restrict__ out) {
    int g = threadIdx.x;
    if (g < G_GRAPHS) {
        float c = fmaxf(cnt[g], 1.0f);
        out[2 * g + 0] = sums[2 * g + 0] / c;
        out[2 * g + 1] = sums[2 * g + 1] / c;
    }
}

// ---- Launch ---------------------------------------------------------------

extern "C" void kernel_launch(void* const* d_in, const int* in_sizes, int n_in,
                              void* d_out, int out_size, void* d_ws, size_t ws_size,
                              hipStream_t stream) {
    const float* x     = (const float*)d_in[0];
    const int*   ei    = (const int*)d_in[1];
    const int*   batch = (const int*)d_in[2];
    const float* W1    = (const float*)d_in[3];
    const float* b1    = (const float*)d_in[4];
    const float* W2    = (const float*)d_in[5];
    const float* b2    = (const float*)d_in[6];
    const float* W3    = (const float*)d_in[7];
    const float* b3    = (const float*)d_in[8];
    float* out = (float*)d_out;

    const int n = in_sizes[0] / 3;
    const int E = in_sizes[1] / 2;
    const int* src = ei;
    const int* dst = ei + E;
    const int nb = (n + BK - 1) >> BK_SHIFT;

    // Workspace layout (4-byte words). Zeroed prefix: bcnt + sums + cnt.
    int* w = (int*)d_ws;
    size_t off = 0;
    auto take = [&](size_t words) { size_t o = off; off = (off + words + 3) & ~(size_t)3; return o; };
    int*      bcnt   = w + take(512);
    float*    sums   = (float*)(w + take(2 * G_GRAPHS));
    float*    cnt    = (float*)(w + take(G_GRAPHS));
    int*      boff   = w + take(NB_MAX + 1);
    int*      cursor = w + take(NB_MAX);
    int*      csr    = w + take(E);
    int*      woff   = w + take((size_t)n + 1);
    float*    dinv   = (float*)(w + take(n));
    float*    p1     = (float*)(w + take(4 * (size_t)n));
    float*    p2     = (float*)(w + take(32 * (size_t)n));
    float*    p3     = (float*)(w + take(2 * (size_t)n));
    // bedge aliases p2 (dead before layer1 writes p2). 32n >= E here; else tail.
    unsigned* bedge  = (32 * (size_t)n >= (size_t)E) ? (unsigned*)p2 : (unsigned*)(w + take(E));

    hipMemsetAsync(d_ws, 0, 896 * 4, stream);

    const int B = 256;
    const int gridN = (n + B - 1) / B;
    const int BINB = 1024;
    const int chunk = (E + BINB - 1) / BINB;
    const int npb = (n + GRID2 - 1) / GRID2;          // 49 for n=100000 (<=52)
    const int nphase = (n + (1 << PH_SHIFT) - 1) >> PH_SHIFT;  // 7

    hist_kernel<<<BINB, B, 0, stream>>>(dst, bcnt, E, nb);
    bscan_kernel<<<1, NB_MAX, 0, stream>>>(bcnt, boff, cursor, nb);
    bin_kernel<<<BINB, B, 0, stream>>>(src, dst, cursor, bedge, E, nb, chunk);
    sort_build<<<nb, BK, 0, stream>>>(bedge, boff, x, csr, woff, dinv, p1, n, E);
    layer1_fused<<<gridN, B, 0, stream>>>(csr, woff, p1, dinv, W1, b1, p2, n);
    gather2_phased<<<GRID2, 256, 0, stream>>>(csr, woff, p2, dinv, W2, b2, W3, p3,
                                              n, npb, nphase);
    layer3_pool<<<gridN, B, 0, stream>>>(csr, woff, p3, dinv, batch, b3, sums, cnt, n);
    finalize_kernel<<<1, 128, 0, stream>>>(sums, cnt, out);
}